// Round 3
// baseline (460.026 us; speedup 1.0000x reference)
//
#include <hip/hip_runtime.h>
#include <math.h>

#define BN 8
#define SN 2048
#define DN 512
#define UN 512
#define MN (BN*SN)   // 16384

typedef _Float16 f16;
typedef _Float16 f16x8 __attribute__((ext_vector_type(8)));
typedef _Float16 f16x4 __attribute__((ext_vector_type(4)));
typedef _Float16 f16x2 __attribute__((ext_vector_type(2)));
typedef float    f32x4 __attribute__((ext_vector_type(4)));
typedef int      i32x4 __attribute__((ext_vector_type(4)));

#define SCALE 0.044194173824159216f   // 1/sqrt(512), folded into W_q at convert
#define LOG2E 1.4426950408889634f
#define DEFER_THR 8.0f

__device__ __forceinline__ void gload_lds16(const f16* g, f16* l) {
  __builtin_amdgcn_global_load_lds(
      (const __attribute__((address_space(1))) unsigned int*)g,
      (__attribute__((address_space(3))) unsigned int*)l, 16, 0, 0);
}

// ---------------- fp32 -> fp16 convert of x ----------------
__global__ __launch_bounds__(256) void cvt_x_kernel(const float* __restrict__ x,
                                                    f16* __restrict__ x16) {
  int i = (blockIdx.x * 256 + threadIdx.x) * 4;
  float4 v = *(const float4*)(x + i);
  f16x4 o = { (f16)v.x, (f16)v.y, (f16)v.z, (f16)v.w };
  *(f16x4*)(x16 + i) = o;
}

// ------------- fp32 -> fp16 convert + transpose of W -------------
// Wt[widx][n][k] = W[k][n]; W_q additionally scaled by 1/sqrt(units).
__global__ __launch_bounds__(256) void cvt_w_kernel(const float* __restrict__ Wq,
                                                    const float* __restrict__ Wk,
                                                    const float* __restrict__ Wv,
                                                    f16* __restrict__ Wt) {
  const float* W = blockIdx.y == 0 ? Wq : (blockIdx.y == 1 ? Wk : Wv);
  const float s = blockIdx.y == 0 ? SCALE : 1.0f;
  f16* o = Wt + (size_t)blockIdx.y * DN * UN;
  int t = blockIdx.x * 256 + threadIdx.x;   // 0..65535
  int r  = t >> 7;          // k row 0..511
  int c4 = (t & 127) * 4;   // n col
  float4 v = *(const float4*)(W + (size_t)r * UN + c4);
  o[(size_t)(c4 + 0) * DN + r] = (f16)(v.x * s);
  o[(size_t)(c4 + 1) * DN + r] = (f16)(v.y * s);
  o[(size_t)(c4 + 2) * DN + r] = (f16)(v.z * s);
  o[(size_t)(c4 + 3) * DN + r] = (f16)(v.w * s);
}

// ---------------- QKV projection GEMM (unchanged structure) ----------------
__global__ __launch_bounds__(256) void qkv_gemm(const f16* __restrict__ x16,
                                                const f16* __restrict__ Wt,
                                                f16* __restrict__ Qh,
                                                f16* __restrict__ Kh,
                                                f16* __restrict__ Vt) {
  __shared__ __align__(16) f16 As[128 * 32];
  __shared__ __align__(16) f16 Bs[128 * 32];

  const int tid = threadIdx.x;
  const int w = tid >> 6, lane = tid & 63;
  const int l15 = lane & 15, lh = lane >> 4;
  const int m0 = blockIdx.x * 128;
  const int n0 = blockIdx.y * 128;
  const int widx = blockIdx.z;
  const f16* Wbase = Wt + (size_t)widx * DN * UN;

  const int wr = (w >> 1) * 64, wc = (w & 1) * 64;
  f32x4 acc[4][4] = {};

  for (int kk = 0; kk < 16; ++kk) {
    const int k0 = kk * 32;
#pragma unroll
    for (int q = 0; q < 2; ++q) {
      int j = q * 256 + tid;           // LDS 16B-chunk index
      int r = j >> 2, cs = j & 3;
      int c = cs ^ ((r >> 1) & 3);     // inverse swizzle on the SOURCE
      f16* abase = &As[(q * 256 + w * 64) * 8];
      f16* bbase = &Bs[(q * 256 + w * 64) * 8];
      gload_lds16(x16 + (size_t)(m0 + r) * DN + k0 + c * 8, abase);
      gload_lds16(Wbase + (size_t)(n0 + r) * DN + k0 + c * 8, bbase);
    }
    __syncthreads();

    f16x8 a[4], bfr[4];
#pragma unroll
    for (int m = 0; m < 4; ++m) {
      int row = wr + m * 16 + l15;
      int ch = lh ^ ((row >> 1) & 3);
      a[m] = *(const f16x8*)&As[row * 32 + ch * 8];
    }
#pragma unroll
    for (int n = 0; n < 4; ++n) {
      int row = wc + n * 16 + l15;
      int ch = lh ^ ((row >> 1) & 3);
      bfr[n] = *(const f16x8*)&Bs[row * 32 + ch * 8];
    }
#pragma unroll
    for (int m = 0; m < 4; ++m)
#pragma unroll
      for (int n = 0; n < 4; ++n)
        acc[m][n] = __builtin_amdgcn_mfma_f32_16x16x32_f16(a[m], bfr[n], acc[m][n], 0, 0, 0);
    __syncthreads();
  }

  if (widx == 2) {
#pragma unroll
    for (int m = 0; m < 4; ++m) {
      int g = m0 + wr + m * 16 + lh * 4;
      int bb = g >> 11;
      int ss = g & 2047;
#pragma unroll
      for (int n = 0; n < 4; ++n) {
        int u = n0 + wc + n * 16 + l15;
        f16x4 pv = { (f16)acc[m][n][0], (f16)acc[m][n][1],
                     (f16)acc[m][n][2], (f16)acc[m][n][3] };
        *(f16x4*)(Vt + ((size_t)bb * UN + u) * SN + ss) = pv;  // V^T[b][u][s]
      }
    }
  } else {
    f16* O = (widx == 0) ? Qh : Kh;
#pragma unroll
    for (int m = 0; m < 4; ++m)
#pragma unroll
      for (int n = 0; n < 4; ++n)
#pragma unroll
        for (int j = 0; j < 4; ++j)
          O[(size_t)(m0 + wr + m * 16 + lh * 4 + j) * UN + (n0 + wc + n * 16 + l15)] =
              (f16)acc[m][n][j];
  }
}

// ---------------- fused flash attention v2 ----------------
// 256 blocks (b = bid&7 XCD-pinned), 512 threads = 8 waves:
// rb = w>>1 (16 q-rows), cs = w&1 (independent kv half-stream, merged at end).
// Swapped QK^T (mfma(K,Q)) -> lane-local P rows, in-register softmax,
// P->PV B-frags via cvt_pkrtz + 8 shfls. K double-buffered in LDS (1 barrier/step).
// V^T read directly from global (L2). acc = O^T partial [full 512 u][16 q].
__global__ __launch_bounds__(512, 2) void attn_kernel(const f16* __restrict__ Qh,
                                                      const f16* __restrict__ Kh,
                                                      const f16* __restrict__ Vt,
                                                      float* __restrict__ out) {
  __shared__ __align__(16) f16 Ks[2][64 * 512];   // 128 KB double-buffered
  __shared__ float redm[4][16];
  __shared__ float redl[4][16];

  const int tid = threadIdx.x;
  const int w = tid >> 6, lane = tid & 63;
  const int l15 = lane & 15, lh = lane >> 4;
  const int bid = blockIdx.x;
  const int b = bid & 7;        // XCD pin: one batch per XCD (K+V = 4MB = L2)
  const int q0 = (bid >> 3) * 64;
  const int rb = w >> 1;
  const int cs = w & 1;

  const f16* Kbat = Kh + (size_t)b * SN * DN;
  const f16* Vbat = Vt + (size_t)b * UN * SN;

  // Q fragments (PV-B-style layout): rows q0+rb*16+l15, k chunks
  const f16* Qbase = Qh + (size_t)(b * SN + q0 + rb * 16 + l15) * DN;
  f16x8 qf[16];
#pragma unroll
  for (int kc = 0; kc < 16; ++kc)
    qf[kc] = *(const f16x8*)(Qbase + kc * 32 + lh * 8);

  f32x4 acc[32] = {};            // O^T partial: u = n*16+lh*4+j, q = l15
  float mrow = -1e30f, lrow = 0.f;

  // prologue: stage tile 0 into Ks[0]
#pragma unroll
  for (int q = 0; q < 8; ++q) {
    int r = w * 8 + q;
    gload_lds16(Kbat + (size_t)r * DN + (lane ^ (r & 7)) * 8, &Ks[0][r * 512]);
  }
  __syncthreads();

  const int swz = (l15 & 7);     // K-read swizzle key (row&7 == l15&7 for both frags)

  for (int t = 0; t < 32; ++t) {
    const int cur = t & 1;
    const int kv0 = t * 64;

    // issue next tile's staging into the other buffer (overlaps all compute)
    if (t < 31) {
#pragma unroll
      for (int q = 0; q < 8; ++q) {
        int r = w * 8 + q;
        gload_lds16(Kbat + (size_t)(kv0 + 64 + r) * DN + (lane ^ (r & 7)) * 8,
                    &Ks[cur ^ 1][r * 512]);
      }
    }

    // ---- QK^T swapped: sc[fc] C-layout col=l15=q, row=lh*4+j=kv (fc*16 offset)
    f32x4 sc0 = {}, sc1 = {};
    const int r0 = cs * 32 + l15;
#pragma unroll
    for (int kc = 0; kc < 16; ++kc) {
      int ch = ((kc * 4 + lh) ^ swz) * 8;
      f16x8 k0 = *(const f16x8*)&Ks[cur][r0 * 512 + ch];
      f16x8 k1 = *(const f16x8*)&Ks[cur][(r0 + 16) * 512 + ch];
      sc0 = __builtin_amdgcn_mfma_f32_16x16x32_f16(k0, qf[kc], sc0, 0, 0, 0);
      sc1 = __builtin_amdgcn_mfma_f32_16x16x32_f16(k1, qf[kc], sc1, 0, 0, 0);
    }

    // ---- in-register online softmax over this wave's 32 kv cols
    float pmax = fmaxf(fmaxf(fmaxf(sc0[0], sc0[1]), fmaxf(sc0[2], sc0[3])),
                       fmaxf(fmaxf(sc1[0], sc1[1]), fmaxf(sc1[2], sc1[3])));
    pmax = fmaxf(pmax, __shfl_xor(pmax, 16, 64));
    pmax = fmaxf(pmax, __shfl_xor(pmax, 32, 64));
    if (!__all(pmax <= mrow + DEFER_THR)) {       // defer-max (T13)
      float mnew = fmaxf(mrow, pmax);
      float rs = exp2f((mrow - mnew) * LOG2E);
      mrow = mnew;
      lrow *= rs;
#pragma unroll
      for (int n = 0; n < 32; ++n) {
        acc[n][0] *= rs; acc[n][1] *= rs; acc[n][2] *= rs; acc[n][3] *= rs;
      }
    }
    float p[8];
#pragma unroll
    for (int j = 0; j < 4; ++j) {
      p[j]     = exp2f((sc0[j] - mrow) * LOG2E);
      p[4 + j] = exp2f((sc1[j] - mrow) * LOG2E);
    }
    float ts = (p[0] + p[1]) + (p[2] + p[3]) + (p[4] + p[5]) + (p[6] + p[7]);
    ts += __shfl_xor(ts, 16, 64);
    ts += __shfl_xor(ts, 32, 64);
    lrow += ts;

    // ---- P -> PV B-fragment (P^T[kv][q]): pack f16 pairs, redistribute via shfl
    // lane holds P[q=l15][kv = fc*16 + lh*4 + j]; B-frag needs kv = lh*8+{0..7}
    int d00 = __builtin_bit_cast(int, __builtin_amdgcn_cvt_pkrtz(p[0], p[1]));
    int d01 = __builtin_bit_cast(int, __builtin_amdgcn_cvt_pkrtz(p[2], p[3]));
    int d10 = __builtin_bit_cast(int, __builtin_amdgcn_cvt_pkrtz(p[4], p[5]));
    int d11 = __builtin_bit_cast(int, __builtin_amdgcn_cvt_pkrtz(p[6], p[7]));
    int srcA = ((lh & 1) << 5) + l15;   // lane (l15, lh_s=2*(lh&1))
    int srcB = srcA + 16;               // lane (l15, lh_s+1)
    int x0 = __shfl(d00, srcA, 64), x1 = __shfl(d01, srcA, 64);
    int y0 = __shfl(d10, srcA, 64), y1 = __shfl(d11, srcA, 64);
    int z0 = __shfl(d00, srcB, 64), z1 = __shfl(d01, srcB, 64);
    int v0 = __shfl(d10, srcB, 64), v1 = __shfl(d11, srcB, 64);
    bool hi = (lh >> 1) != 0;           // which source frag (fc) we need
    i32x4 pw = { hi ? y0 : x0, hi ? y1 : x1, hi ? v0 : z0, hi ? v1 : z1 };
    f16x8 pb = __builtin_bit_cast(f16x8, pw);

    // ---- PV: O^T += V^T_frag * P^T_frag  (V^T direct from global/L2)
    const f16* vb = Vbat + (size_t)l15 * SN + kv0 + cs * 32 + lh * 8;
#pragma unroll
    for (int n = 0; n < 32; ++n) {
      f16x8 vf = *(const f16x8*)(vb + (size_t)(n * 16) * SN);
      acc[n] = __builtin_amdgcn_mfma_f32_16x16x32_f16(vf, pb, acc[n], 0, 0, 0);
    }

    __syncthreads();   // staging of tile t+1 complete; safe to flip buffers
  }

  // ---- merge the two kv-streams (cs=0 and cs=1) of each row-group
  float* xfer = (float*)&Ks[0][0];      // retired K buffers: 128KB = 4 rb * 32KB
  if (cs == 1) {
    if (lh == 0) { redm[rb][l15] = mrow; redl[rb][l15] = lrow; }
    float* dst = xfer + rb * 8192 + (lh * 16 + l15) * 4;
#pragma unroll
    for (int n = 0; n < 32; ++n) *(f32x4*)(dst + n * 256) = acc[n];
  }
  __syncthreads();
  if (cs == 0) {
    float m1 = redm[rb][l15], l1 = redl[rb][l15];
    float M = fmaxf(mrow, m1);
    float f0 = exp2f((mrow - M) * LOG2E);
    float f1 = exp2f((m1 - M) * LOG2E);
    float inv = 1.0f / (lrow * f0 + l1 * f1);
    const float* src = xfer + rb * 8192 + (lh * 16 + l15) * 4;
    float* obase = out + ((size_t)(b * SN + q0 + rb * 16 + l15)) * UN + lh * 4;
#pragma unroll
    for (int n = 0; n < 32; ++n) {
      f32x4 a1 = *(const f32x4*)(src + n * 256);
      f32x4 o;
      o[0] = (acc[n][0] * f0 + a1[0] * f1) * inv;
      o[1] = (acc[n][1] * f0 + a1[1] * f1) * inv;
      o[2] = (acc[n][2] * f0 + a1[2] * f1) * inv;
      o[3] = (acc[n][3] * f0 + a1[3] * f1) * inv;
      *(f32x4*)(obase + n * 16) = o;
    }
  }
}

extern "C" void kernel_launch(void* const* d_in, const int* in_sizes, int n_in,
                              void* d_out, int out_size, void* d_ws, size_t ws_size,
                              hipStream_t stream) {
  const float* x  = (const float*)d_in[0];
  const float* Wq = (const float*)d_in[1];
  const float* Wk = (const float*)d_in[2];
  const float* Wv = (const float*)d_in[3];
  float* out = (float*)d_out;

  f16* x16 = (f16*)d_ws;
  f16* Wt  = x16 + (size_t)MN * DN;
  f16* Qh  = Wt + (size_t)3 * DN * UN;
  f16* Kh  = Qh + (size_t)MN * UN;
  f16* Vt  = Kh + (size_t)MN * UN;

  cvt_x_kernel<<<dim3(MN * DN / 1024), 256, 0, stream>>>(x, x16);
  cvt_w_kernel<<<dim3(256, 3), 256, 0, stream>>>(Wq, Wk, Wv, Wt);
  qkv_gemm<<<dim3(128, 4, 3), 256, 0, stream>>>(x16, Wt, Qh, Kh, Vt);
  attn_kernel<<<256, 512, 0, stream>>>(Qh, Kh, Vt, out);
}